// Round 2
// baseline (1066.272 us; speedup 1.0000x reference)
//
#include <hip/hip_runtime.h>
#include <hip/hip_fp16.h>

#define N_NODES 200000
#define N_EDGES 6400000
#define IN_FEAT 128
#define HIDDEN  16

// ---- counting-sort geometry: 782 ranges x 256 nodes; edge packed as (local<<18)|src ----
#define RN 256
#define NR 782                 // 782*256 = 200192 >= N_NODES
#define SRC_MASK 0x3FFFFu      // 18 bits, N_NODES < 262144
#define SB 8192                // edges per scatter block

typedef float v4f __attribute__((ext_vector_type(4)));
typedef _Float16 f16x8 __attribute__((ext_vector_type(8)));
typedef float f32x4 __attribute__((ext_vector_type(4)));

// ---------------- bucket count: per-range edge histogram ----------------

__global__ __launch_bounds__(256) void k_bcnt(const int* __restrict__ col,
                                              unsigned* __restrict__ bcnt) {
    __shared__ unsigned c[NR];
    for (int i = threadIdx.x; i < NR; i += 256) c[i] = 0u;
    __syncthreads();
    const int EPB = N_EDGES / 512;            // 12500
    const int4* c4 = (const int4*)(col + (size_t)blockIdx.x * EPB);
    for (int i = threadIdx.x; i < EPB / 4; i += 256) {
        int4 v = c4[i];
        atomicAdd(&c[(unsigned)v.x >> 8], 1u);
        atomicAdd(&c[(unsigned)v.y >> 8], 1u);
        atomicAdd(&c[(unsigned)v.z >> 8], 1u);
        atomicAdd(&c[(unsigned)v.w >> 8], 1u);
    }
    __syncthreads();
    for (int i = threadIdx.x; i < NR; i += 256)
        if (c[i]) atomicAdd(&bcnt[i], c[i]);
}

// ---------------- exclusive scan over 782 buckets (1 block, Hillis-Steele) ----------------

__global__ __launch_bounds__(1024) void k_scan(const unsigned* __restrict__ bcnt,
                                               unsigned* __restrict__ boffs,
                                               unsigned* __restrict__ bcur) {
    __shared__ unsigned s[1024];
    const int t = threadIdx.x;
    unsigned v = (t < NR) ? bcnt[t] : 0u;
    s[t] = v;
    __syncthreads();
    #pragma unroll
    for (int d = 1; d < 1024; d <<= 1) {
        unsigned add = (t >= d) ? s[t - d] : 0u;
        __syncthreads();
        s[t] += add;
        __syncthreads();
    }
    if (t < NR) {
        unsigned excl = s[t] - v;
        boffs[t] = excl;
        bcur[t] = excl;
        if (t == NR - 1) boffs[NR] = s[t];
    }
}

// ---------------- scatter edges into range-sorted u32 array ----------------

__global__ __launch_bounds__(256) void k_bscat(const int* __restrict__ row,
                                               const int* __restrict__ col,
                                               unsigned* __restrict__ bcur,
                                               unsigned* __restrict__ sorted) {
    __shared__ unsigned cnt[NR], gbase[NR], lcur[NR];
    const long long e0 = (long long)blockIdx.x * SB;
    long long rem = (long long)N_EDGES - e0;
    const int n = rem > SB ? SB : (int)rem;   // always a multiple of 4 here
    for (int i = threadIdx.x; i < NR; i += 256) { cnt[i] = 0u; lcur[i] = 0u; }
    __syncthreads();
    const int4* c4 = (const int4*)(col + e0);
    for (int i = threadIdx.x; i < n / 4; i += 256) {
        int4 v = c4[i];
        atomicAdd(&cnt[(unsigned)v.x >> 8], 1u);
        atomicAdd(&cnt[(unsigned)v.y >> 8], 1u);
        atomicAdd(&cnt[(unsigned)v.z >> 8], 1u);
        atomicAdd(&cnt[(unsigned)v.w >> 8], 1u);
    }
    __syncthreads();
    for (int i = threadIdx.x; i < NR; i += 256)
        gbase[i] = cnt[i] ? atomicAdd(&bcur[i], cnt[i]) : 0u;
    __syncthreads();
    for (int i = threadIdx.x; i < n; i += 256) {
        unsigned c = (unsigned)col[e0 + i];
        unsigned s = (unsigned)row[e0 + i];
        unsigned r = c >> 8;
        unsigned pos = gbase[r] + atomicAdd(&lcur[r], 1u);
        sorted[pos] = ((c & (RN - 1u)) << 18) | s;
    }
}

// ---------------- degrees + dinv from sorted buckets ----------------

__global__ __launch_bounds__(256) void k_deg(const unsigned* __restrict__ sorted,
                                             const unsigned* __restrict__ boffs,
                                             float* __restrict__ dinv) {
    __shared__ unsigned dg[RN];
    const int r = blockIdx.x;
    const unsigned lo = boffs[r], hi = boffs[r + 1];
    const unsigned node0 = (unsigned)r * RN;
    if (threadIdx.x < RN) dg[threadIdx.x] = 0u;
    __syncthreads();
    for (unsigned e = lo + threadIdx.x; e < hi; e += 256)
        atomicAdd(&dg[sorted[e] >> 18], 1u);
    __syncthreads();
    if (threadIdx.x < RN) {
        unsigned node = node0 + threadIdx.x;
        if (node < N_NODES) dinv[node] = rsqrtf((float)dg[threadIdx.x] + 1.0f);  // +1 self-loop
    }
}

// ---------------- layer-1 GEMM via MFMA: h16 = dinv .* (x @ W1), fp16 ----------------

__global__ __launch_bounds__(256) void k_gemm1(const float* __restrict__ x,
                                               const float* __restrict__ W1,
                                               const float* __restrict__ dinv,
                                               __half* __restrict__ h16) {
    const int wave = (blockIdx.x * 256 + threadIdx.x) >> 6;   // tile id
    const int lane = threadIdx.x & 63;
    const int m16 = lane & 15;
    const int quad = lane >> 4;
    if (wave * 16 >= N_NODES) return;

    f16x8 bf[4];
    #pragma unroll
    for (int kb = 0; kb < 4; ++kb)
        #pragma unroll
        for (int j = 0; j < 8; ++j)
            bf[kb][j] = (_Float16)W1[(kb * 32 + quad * 8 + j) * HIDDEN + m16];

    const int node0 = wave * 16;
    const float* xrow = x + (size_t)(node0 + m16) * IN_FEAT + quad * 8;
    f32x4 acc = {0.f, 0.f, 0.f, 0.f};
    #pragma unroll
    for (int kb = 0; kb < 4; ++kb) {
        const v4f* p = (const v4f*)(xrow + kb * 32);
        v4f u0 = p[0], u1 = p[1];
        f16x8 af;
        af[0] = (_Float16)u0.x; af[1] = (_Float16)u0.y;
        af[2] = (_Float16)u0.z; af[3] = (_Float16)u0.w;
        af[4] = (_Float16)u1.x; af[5] = (_Float16)u1.y;
        af[6] = (_Float16)u1.z; af[7] = (_Float16)u1.w;
        acc = __builtin_amdgcn_mfma_f32_16x16x32_f16(af, bf[kb], acc, 0, 0, 0);
    }
    #pragma unroll
    for (int r = 0; r < 4; ++r) {
        int node = node0 + quad * 4 + r;
        h16[(size_t)node * HIDDEN + m16] = __float2half(dinv[node] * acc[r]);
    }
}

// ---------------- layer-1 aggregation per range (f32 LDS) + fused node2 ----------------

__global__ __launch_bounds__(512) void k_agg1(const unsigned* __restrict__ sorted,
                                              const unsigned* __restrict__ boffs,
                                              const unsigned* __restrict__ h16u,
                                              const float* __restrict__ dinv,
                                              const float* __restrict__ b1,
                                              const float* __restrict__ W2,
                                              float* __restrict__ tp) {
    __shared__ float hs[RN][16];                  // 16 KB
    const int r = blockIdx.x;
    const unsigned lo = boffs[r], hi = boffs[r + 1];
    const unsigned node0 = (unsigned)r * RN;
    float* hsf = &hs[0][0];
    for (int i = threadIdx.x; i < RN * 16; i += 512) hsf[i] = 0.f;
    __syncthreads();

    // 8 threads per edge: thread l handles features 2l, 2l+1
    const int l = threadIdx.x & 7;
    unsigned e = lo + (threadIdx.x >> 3);
    for (; e + 192 < hi; e += 256) {              // 4-deep ILP
        unsigned p0 = sorted[e];
        unsigned p1 = sorted[e + 64];
        unsigned p2 = sorted[e + 128];
        unsigned p3 = sorted[e + 192];
        unsigned v0 = h16u[(size_t)(p0 & SRC_MASK) * 8 + l];
        unsigned v1 = h16u[(size_t)(p1 & SRC_MASK) * 8 + l];
        unsigned v2 = h16u[(size_t)(p2 & SRC_MASK) * 8 + l];
        unsigned v3 = h16u[(size_t)(p3 & SRC_MASK) * 8 + l];
        float2 f0 = __half22float2(*(const __half2*)&v0);
        float2 f1 = __half22float2(*(const __half2*)&v1);
        float2 f2 = __half22float2(*(const __half2*)&v2);
        float2 f3 = __half22float2(*(const __half2*)&v3);
        unsafeAtomicAdd(&hs[p0 >> 18][2 * l],     f0.x);
        unsafeAtomicAdd(&hs[p0 >> 18][2 * l + 1], f0.y);
        unsafeAtomicAdd(&hs[p1 >> 18][2 * l],     f1.x);
        unsafeAtomicAdd(&hs[p1 >> 18][2 * l + 1], f1.y);
        unsafeAtomicAdd(&hs[p2 >> 18][2 * l],     f2.x);
        unsafeAtomicAdd(&hs[p2 >> 18][2 * l + 1], f2.y);
        unsafeAtomicAdd(&hs[p3 >> 18][2 * l],     f3.x);
        unsafeAtomicAdd(&hs[p3 >> 18][2 * l + 1], f3.y);
    }
    for (; e < hi; e += 64) {
        unsigned p = sorted[e];
        unsigned v = h16u[(size_t)(p & SRC_MASK) * 8 + l];
        float2 f = __half22float2(*(const __half2*)&v);
        unsafeAtomicAdd(&hs[p >> 18][2 * l],     f.x);
        unsafeAtomicAdd(&hs[p >> 18][2 * l + 1], f.y);
    }
    __syncthreads();

    // fused node2: t' = dinv * sum_k relu(dinv*(agg_k + self_k) + b1_k) * W2_k
    float b1r[16], w2r[16];
    #pragma unroll
    for (int k = 0; k < 16; ++k) { b1r[k] = b1[k]; w2r[k] = W2[k]; }
    for (int i = threadIdx.x; i < RN; i += 512) {
        unsigned node = node0 + i;
        if (node >= N_NODES) continue;
        float di = dinv[node];
        union { int4 v[2]; __half h[16]; } u;
        const int4* hp = (const int4*)(h16u + (size_t)node * 8);
        u.v[0] = hp[0]; u.v[1] = hp[1];
        float acc = 0.f;
        #pragma unroll
        for (int k = 0; k < 16; ++k) {
            float pre = fmaf(di, hs[i][k] + __half2float(u.h[k]), b1r[k]);
            acc = fmaf(fmaxf(pre, 0.f), w2r[k], acc);
        }
        tp[node] = di * acc;
    }
}

// ---------------- layer-2 aggregation per range + fused finalize ----------------

__global__ __launch_bounds__(256) void k_agg2(const unsigned* __restrict__ sorted,
                                              const unsigned* __restrict__ boffs,
                                              const float* __restrict__ tp,
                                              const float* __restrict__ dinv,
                                              const float* __restrict__ b2,
                                              float* __restrict__ out) {
    __shared__ float ht[RN];                      // 1 KB
    const int r = blockIdx.x;
    const unsigned lo = boffs[r], hi = boffs[r + 1];
    const unsigned node0 = (unsigned)r * RN;
    if (threadIdx.x < RN) ht[threadIdx.x] = 0.f;
    __syncthreads();
    unsigned e = lo + threadIdx.x;
    for (; e + 768 < hi; e += 1024) {             // 4-deep ILP
        unsigned p0 = sorted[e];
        unsigned p1 = sorted[e + 256];
        unsigned p2 = sorted[e + 512];
        unsigned p3 = sorted[e + 768];
        float t0 = tp[p0 & SRC_MASK];
        float t1 = tp[p1 & SRC_MASK];
        float t2 = tp[p2 & SRC_MASK];
        float t3 = tp[p3 & SRC_MASK];
        unsafeAtomicAdd(&ht[p0 >> 18], t0);
        unsafeAtomicAdd(&ht[p1 >> 18], t1);
        unsafeAtomicAdd(&ht[p2 >> 18], t2);
        unsafeAtomicAdd(&ht[p3 >> 18], t3);
    }
    for (; e < hi; e += 256) {
        unsigned p = sorted[e];
        unsafeAtomicAdd(&ht[p >> 18], tp[p & SRC_MASK]);
    }
    __syncthreads();
    if (threadIdx.x < RN) {
        unsigned node = node0 + threadIdx.x;
        if (node < N_NODES)
            out[node] = fmaf(dinv[node], tp[node] + ht[threadIdx.x], b2[0]);
    }
}

// ---------------- launch ----------------

extern "C" void kernel_launch(void* const* d_in, const int* in_sizes, int n_in,
                              void* d_out, int out_size, void* d_ws, size_t ws_size,
                              hipStream_t stream) {
    const float* x   = (const float*)d_in[0];
    const int*   ei  = (const int*)d_in[1];
    const float* W1  = (const float*)d_in[2];
    const float* b1  = (const float*)d_in[3];
    const float* W2  = (const float*)d_in[4];
    const float* b2  = (const float*)d_in[5];
    float* out = (float*)d_out;

    const int* row = ei;               // sources
    const int* col = ei + N_EDGES;     // targets

    // ws: [bcnt 1024][boffs 1024][bcur 1024][dinv N f32][tp N f32][h16 16N fp16][sorted E u32]
    unsigned* bcnt  = (unsigned*)d_ws;
    unsigned* boffs = bcnt + 1024;
    unsigned* bcur  = boffs + 1024;
    float*    dinv  = (float*)(bcur + 1024);
    float*    tp    = dinv + N_NODES;
    __half*   h16   = (__half*)(tp + N_NODES);
    unsigned* sorted = (unsigned*)(h16 + (size_t)N_NODES * HIDDEN);

    (void)hipMemsetAsync(bcnt, 0, 1024 * sizeof(unsigned), stream);
    k_bcnt<<<512, 256, 0, stream>>>(col, bcnt);
    k_scan<<<1, 1024, 0, stream>>>(bcnt, boffs, bcur);
    k_bscat<<<(N_EDGES + SB - 1) / SB, 256, 0, stream>>>(row, col, bcur, sorted);
    k_deg<<<NR, 256, 0, stream>>>(sorted, boffs, dinv);
    k_gemm1<<<(N_NODES / 16 + 3) / 4, 256, 0, stream>>>(x, W1, dinv, h16);
    k_agg1<<<NR, 512, 0, stream>>>(sorted, boffs, (const unsigned*)h16, dinv, b1, W2, tp);
    k_agg2<<<NR, 256, 0, stream>>>(sorted, boffs, tp, dinv, b2, out);
}

// Round 3
// 1011.658 us; speedup vs baseline: 1.0540x; 1.0540x over previous
//
#include <hip/hip_runtime.h>
#include <hip/hip_fp16.h>

#define N_NODES 200000
#define N_EDGES 6400000
#define IN_FEAT 128
#define HIDDEN  16

// ---- counting-sort geometry: 1563 ranges x 128 nodes; edge packed as (local<<18)|src ----
#define RN 128
#define RSHIFT 7
#define NR 1563                // 1563*128 = 200064 >= N_NODES
#define SRC_MASK 0x3FFFFu      // 18 bits, N_NODES < 262144
#define SB 4096                // edges per scatter block

typedef float v4f __attribute__((ext_vector_type(4)));
typedef _Float16 f16x8 __attribute__((ext_vector_type(8)));
typedef float f32x4 __attribute__((ext_vector_type(4)));

// ---------------- bucket count: per-range edge histogram ----------------

__global__ __launch_bounds__(256) void k_bcnt(const int* __restrict__ col,
                                              unsigned* __restrict__ bcnt) {
    __shared__ unsigned c[NR];
    for (int i = threadIdx.x; i < NR; i += 256) c[i] = 0u;
    __syncthreads();
    const int EPB = N_EDGES / 512;            // 12500
    const int4* c4 = (const int4*)(col + (size_t)blockIdx.x * EPB);
    for (int i = threadIdx.x; i < EPB / 4; i += 256) {
        int4 v = c4[i];
        atomicAdd(&c[(unsigned)v.x >> RSHIFT], 1u);
        atomicAdd(&c[(unsigned)v.y >> RSHIFT], 1u);
        atomicAdd(&c[(unsigned)v.z >> RSHIFT], 1u);
        atomicAdd(&c[(unsigned)v.w >> RSHIFT], 1u);
    }
    __syncthreads();
    for (int i = threadIdx.x; i < NR; i += 256)
        if (c[i]) atomicAdd(&bcnt[i], c[i]);
}

// ------------- exclusive scan over 1563 buckets (1 block, 2 elems/thread) -------------

__global__ __launch_bounds__(1024) void k_scan(const unsigned* __restrict__ bcnt,
                                               unsigned* __restrict__ boffs,
                                               unsigned* __restrict__ bcur) {
    __shared__ unsigned s[1024];
    const int t = threadIdx.x;
    unsigned c0 = (2 * t     < NR) ? bcnt[2 * t]     : 0u;
    unsigned c1 = (2 * t + 1 < NR) ? bcnt[2 * t + 1] : 0u;
    unsigned pairsum = c0 + c1;
    s[t] = pairsum;
    __syncthreads();
    #pragma unroll
    for (int d = 1; d < 1024; d <<= 1) {
        unsigned add = (t >= d) ? s[t - d] : 0u;
        __syncthreads();
        s[t] += add;
        __syncthreads();
    }
    unsigned excl = s[t] - pairsum;
    if (2 * t < NR)     { boffs[2 * t]     = excl;      bcur[2 * t]     = excl; }
    if (2 * t + 1 < NR) { boffs[2 * t + 1] = excl + c0; bcur[2 * t + 1] = excl + c0; }
    if (t == 1023) boffs[NR] = s[t];
}

// ---------------- scatter edges into range-sorted u32 array ----------------

__global__ __launch_bounds__(256) void k_bscat(const int* __restrict__ row,
                                               const int* __restrict__ col,
                                               unsigned* __restrict__ bcur,
                                               unsigned* __restrict__ sorted) {
    __shared__ unsigned cnt[NR], gbase[NR], lcur[NR];   // 18.8 KB
    const long long e0 = (long long)blockIdx.x * SB;
    long long rem = (long long)N_EDGES - e0;
    const int n = rem > SB ? SB : (int)rem;   // multiple of 4
    for (int i = threadIdx.x; i < NR; i += 256) { cnt[i] = 0u; lcur[i] = 0u; }
    __syncthreads();
    const int4* c4 = (const int4*)(col + e0);
    for (int i = threadIdx.x; i < n / 4; i += 256) {
        int4 v = c4[i];
        atomicAdd(&cnt[(unsigned)v.x >> RSHIFT], 1u);
        atomicAdd(&cnt[(unsigned)v.y >> RSHIFT], 1u);
        atomicAdd(&cnt[(unsigned)v.z >> RSHIFT], 1u);
        atomicAdd(&cnt[(unsigned)v.w >> RSHIFT], 1u);
    }
    __syncthreads();
    for (int i = threadIdx.x; i < NR; i += 256)
        gbase[i] = cnt[i] ? atomicAdd(&bcur[i], cnt[i]) : 0u;
    __syncthreads();
    for (int i = threadIdx.x; i < n; i += 256) {
        unsigned c = (unsigned)col[e0 + i];
        unsigned s = (unsigned)row[e0 + i];
        unsigned r = c >> RSHIFT;
        unsigned pos = gbase[r] + atomicAdd(&lcur[r], 1u);
        sorted[pos] = ((c & (RN - 1u)) << 18) | s;
    }
}

// ---------------- degrees + dinv from sorted buckets ----------------

__global__ __launch_bounds__(256) void k_deg(const unsigned* __restrict__ sorted,
                                             const unsigned* __restrict__ boffs,
                                             float* __restrict__ dinv) {
    __shared__ unsigned dg[RN];
    const int r = blockIdx.x;
    const unsigned lo = boffs[r], hi = boffs[r + 1];
    const unsigned node0 = (unsigned)r * RN;
    if (threadIdx.x < RN) dg[threadIdx.x] = 0u;
    __syncthreads();
    for (unsigned e = lo + threadIdx.x; e < hi; e += 256)
        atomicAdd(&dg[sorted[e] >> 18], 1u);
    __syncthreads();
    if (threadIdx.x < RN) {
        unsigned node = node0 + threadIdx.x;
        if (node < N_NODES) dinv[node] = rsqrtf((float)dg[threadIdx.x] + 1.0f);  // +1 self-loop
    }
}

// ---------------- layer-1 GEMM via MFMA: h16 = dinv .* (x @ W1), fp16 ----------------

__global__ __launch_bounds__(256) void k_gemm1(const float* __restrict__ x,
                                               const float* __restrict__ W1,
                                               const float* __restrict__ dinv,
                                               __half* __restrict__ h16) {
    const int wave = (blockIdx.x * 256 + threadIdx.x) >> 6;   // tile id
    const int lane = threadIdx.x & 63;
    const int m16 = lane & 15;
    const int quad = lane >> 4;
    if (wave * 16 >= N_NODES) return;

    f16x8 bf[4];
    #pragma unroll
    for (int kb = 0; kb < 4; ++kb)
        #pragma unroll
        for (int j = 0; j < 8; ++j)
            bf[kb][j] = (_Float16)W1[(kb * 32 + quad * 8 + j) * HIDDEN + m16];

    const int node0 = wave * 16;
    const float* xrow = x + (size_t)(node0 + m16) * IN_FEAT + quad * 8;
    f32x4 acc = {0.f, 0.f, 0.f, 0.f};
    #pragma unroll
    for (int kb = 0; kb < 4; ++kb) {
        const v4f* p = (const v4f*)(xrow + kb * 32);
        v4f u0 = p[0], u1 = p[1];
        f16x8 af;
        af[0] = (_Float16)u0.x; af[1] = (_Float16)u0.y;
        af[2] = (_Float16)u0.z; af[3] = (_Float16)u0.w;
        af[4] = (_Float16)u1.x; af[5] = (_Float16)u1.y;
        af[6] = (_Float16)u1.z; af[7] = (_Float16)u1.w;
        acc = __builtin_amdgcn_mfma_f32_16x16x32_f16(af, bf[kb], acc, 0, 0, 0);
    }
    #pragma unroll
    for (int r = 0; r < 4; ++r) {
        int node = node0 + quad * 4 + r;
        h16[(size_t)node * HIDDEN + m16] = __float2half(dinv[node] * acc[r]);
    }
}

// ------- layer-1 aggregation per range (f32 LDS, stride-17 pad) + fused node2 -------

__global__ __launch_bounds__(256, 8) void k_agg1(const unsigned* __restrict__ sorted,
                                                 const unsigned* __restrict__ boffs,
                                                 const unsigned* __restrict__ h16u,
                                                 const float* __restrict__ dinv,
                                                 const float* __restrict__ b1,
                                                 const float* __restrict__ W2,
                                                 float* __restrict__ tp) {
    __shared__ float hs[RN][17];                  // 8.7 KB, stride 17 kills bank pathology
    const int r = blockIdx.x;
    const unsigned lo = boffs[r], hi = boffs[r + 1];
    const unsigned node0 = (unsigned)r * RN;
    float* hsf = &hs[0][0];
    for (int i = threadIdx.x; i < RN * 17; i += 256) hsf[i] = 0.f;
    __syncthreads();

    // 8 threads per edge: thread l handles features 2l, 2l+1; 32 edge slots, 8-deep ILP
    const int l = threadIdx.x & 7;
    unsigned e = lo + (threadIdx.x >> 3);
    for (; e + 224 < hi; e += 256) {
        unsigned p0 = sorted[e];
        unsigned p1 = sorted[e + 32];
        unsigned p2 = sorted[e + 64];
        unsigned p3 = sorted[e + 96];
        unsigned p4 = sorted[e + 128];
        unsigned p5 = sorted[e + 160];
        unsigned p6 = sorted[e + 192];
        unsigned p7 = sorted[e + 224];
        unsigned v0 = h16u[(size_t)(p0 & SRC_MASK) * 8 + l];
        unsigned v1 = h16u[(size_t)(p1 & SRC_MASK) * 8 + l];
        unsigned v2 = h16u[(size_t)(p2 & SRC_MASK) * 8 + l];
        unsigned v3 = h16u[(size_t)(p3 & SRC_MASK) * 8 + l];
        unsigned v4 = h16u[(size_t)(p4 & SRC_MASK) * 8 + l];
        unsigned v5 = h16u[(size_t)(p5 & SRC_MASK) * 8 + l];
        unsigned v6 = h16u[(size_t)(p6 & SRC_MASK) * 8 + l];
        unsigned v7 = h16u[(size_t)(p7 & SRC_MASK) * 8 + l];
        float2 f;
        f = __half22float2(*(const __half2*)&v0);
        atomicAdd(&hs[p0 >> 18][2 * l], f.x); atomicAdd(&hs[p0 >> 18][2 * l + 1], f.y);
        f = __half22float2(*(const __half2*)&v1);
        atomicAdd(&hs[p1 >> 18][2 * l], f.x); atomicAdd(&hs[p1 >> 18][2 * l + 1], f.y);
        f = __half22float2(*(const __half2*)&v2);
        atomicAdd(&hs[p2 >> 18][2 * l], f.x); atomicAdd(&hs[p2 >> 18][2 * l + 1], f.y);
        f = __half22float2(*(const __half2*)&v3);
        atomicAdd(&hs[p3 >> 18][2 * l], f.x); atomicAdd(&hs[p3 >> 18][2 * l + 1], f.y);
        f = __half22float2(*(const __half2*)&v4);
        atomicAdd(&hs[p4 >> 18][2 * l], f.x); atomicAdd(&hs[p4 >> 18][2 * l + 1], f.y);
        f = __half22float2(*(const __half2*)&v5);
        atomicAdd(&hs[p5 >> 18][2 * l], f.x); atomicAdd(&hs[p5 >> 18][2 * l + 1], f.y);
        f = __half22float2(*(const __half2*)&v6);
        atomicAdd(&hs[p6 >> 18][2 * l], f.x); atomicAdd(&hs[p6 >> 18][2 * l + 1], f.y);
        f = __half22float2(*(const __half2*)&v7);
        atomicAdd(&hs[p7 >> 18][2 * l], f.x); atomicAdd(&hs[p7 >> 18][2 * l + 1], f.y);
    }
    for (; e < hi; e += 32) {
        unsigned p = sorted[e];
        unsigned v = h16u[(size_t)(p & SRC_MASK) * 8 + l];
        float2 f = __half22float2(*(const __half2*)&v);
        atomicAdd(&hs[p >> 18][2 * l],     f.x);
        atomicAdd(&hs[p >> 18][2 * l + 1], f.y);
    }
    __syncthreads();

    // fused node2: t' = dinv * sum_k relu(dinv*(agg_k + self_k) + b1_k) * W2_k
    if (threadIdx.x < RN) {
        const int i = threadIdx.x;
        unsigned node = node0 + i;
        if (node < N_NODES) {
            float di = dinv[node];
            union { int4 v[2]; __half h[16]; } u;
            const int4* hp = (const int4*)(h16u + (size_t)node * 8);
            u.v[0] = hp[0]; u.v[1] = hp[1];
            float acc = 0.f;
            #pragma unroll
            for (int k = 0; k < 16; ++k) {
                float pre = fmaf(di, hs[i][k] + __half2float(u.h[k]), b1[k]);
                acc = fmaf(fmaxf(pre, 0.f), W2[k], acc);
            }
            tp[node] = di * acc;
        }
    }
}

// ---------------- layer-2 aggregation per range + fused finalize ----------------

__global__ __launch_bounds__(256, 8) void k_agg2(const unsigned* __restrict__ sorted,
                                                 const unsigned* __restrict__ boffs,
                                                 const float* __restrict__ tp,
                                                 const float* __restrict__ dinv,
                                                 const float* __restrict__ b2,
                                                 float* __restrict__ out) {
    __shared__ float ht[RN];                      // 512 B
    const int r = blockIdx.x;
    const unsigned lo = boffs[r], hi = boffs[r + 1];
    const unsigned node0 = (unsigned)r * RN;
    if (threadIdx.x < RN) ht[threadIdx.x] = 0.f;
    __syncthreads();
    unsigned e = lo + threadIdx.x;
    for (; e + 768 < hi; e += 1024) {             // 4-deep ILP
        unsigned p0 = sorted[e];
        unsigned p1 = sorted[e + 256];
        unsigned p2 = sorted[e + 512];
        unsigned p3 = sorted[e + 768];
        float t0 = tp[p0 & SRC_MASK];
        float t1 = tp[p1 & SRC_MASK];
        float t2 = tp[p2 & SRC_MASK];
        float t3 = tp[p3 & SRC_MASK];
        atomicAdd(&ht[p0 >> 18], t0);
        atomicAdd(&ht[p1 >> 18], t1);
        atomicAdd(&ht[p2 >> 18], t2);
        atomicAdd(&ht[p3 >> 18], t3);
    }
    for (; e < hi; e += 256) {
        unsigned p = sorted[e];
        atomicAdd(&ht[p >> 18], tp[p & SRC_MASK]);
    }
    __syncthreads();
    if (threadIdx.x < RN) {
        unsigned node = node0 + threadIdx.x;
        if (node < N_NODES)
            out[node] = fmaf(dinv[node], tp[node] + ht[threadIdx.x], b2[0]);
    }
}

// ---------------- launch ----------------

extern "C" void kernel_launch(void* const* d_in, const int* in_sizes, int n_in,
                              void* d_out, int out_size, void* d_ws, size_t ws_size,
                              hipStream_t stream) {
    const float* x   = (const float*)d_in[0];
    const int*   ei  = (const int*)d_in[1];
    const float* W1  = (const float*)d_in[2];
    const float* b1  = (const float*)d_in[3];
    const float* W2  = (const float*)d_in[4];
    const float* b2  = (const float*)d_in[5];
    float* out = (float*)d_out;

    const int* row = ei;               // sources
    const int* col = ei + N_EDGES;     // targets

    // ws: [bcnt 2048][boffs 2048][bcur 2048][dinv N f32][tp N f32][h16 16N fp16][sorted E u32]
    unsigned* bcnt  = (unsigned*)d_ws;
    unsigned* boffs = bcnt + 2048;
    unsigned* bcur  = boffs + 2048;
    float*    dinv  = (float*)(bcur + 2048);
    float*    tp    = dinv + N_NODES;
    __half*   h16   = (__half*)(tp + N_NODES);
    unsigned* sorted = (unsigned*)(h16 + (size_t)N_NODES * HIDDEN);

    (void)hipMemsetAsync(bcnt, 0, 2048 * sizeof(unsigned), stream);
    k_bcnt<<<512, 256, 0, stream>>>(col, bcnt);
    k_scan<<<1, 1024, 0, stream>>>(bcnt, boffs, bcur);
    k_bscat<<<(N_EDGES + SB - 1) / SB, 256, 0, stream>>>(row, col, bcur, sorted);
    k_deg<<<NR, 256, 0, stream>>>(sorted, boffs, dinv);
    k_gemm1<<<(N_NODES / 16 + 3) / 4, 256, 0, stream>>>(x, W1, dinv, h16);
    k_agg1<<<NR, 256, 0, stream>>>(sorted, boffs, (const unsigned*)h16, dinv, b1, W2, tp);
    k_agg2<<<NR, 256, 0, stream>>>(sorted, boffs, tp, dinv, b2, out);
}